// Round 10
// baseline (331.278 us; speedup 1.0000x reference)
//
#include <hip/hip_runtime.h>
#include <math.h>

#define H 128
#define NBUCK_MAX 256  // coarse buckets = (N+255)>>8; requires N <= 65536

typedef _Float16 half8 __attribute__((ext_vector_type(8)));
typedef float f32x16 __attribute__((ext_vector_type(16)));
typedef int int4v __attribute__((ext_vector_type(4)));

__device__ __forceinline__ half8 h8max(half8 a, half8 b) {
#if defined(__has_builtin) && __has_builtin(__builtin_elementwise_max)
    return __builtin_elementwise_max(a, b);
#else
    half8 r;
#pragma unroll
    for (int j = 0; j < 8; ++j) r[j] = a[j] > b[j] ? a[j] : b[j];
    return r;
#endif
}

__device__ __forceinline__ half8 h8shfl_xor(half8 v, int mask) {
    int4v iv;
    __builtin_memcpy(&iv, &v, 16);
#pragma unroll
    for (int j = 0; j < 4; ++j) iv[j] = __shfl_xor(iv[j], mask, 64);
    half8 r;
    __builtin_memcpy(&r, &iv, 16);
    return r;
}

// ---------------- merged prep ----------------
// Round-9 diagnosis: the edge scatter was random-traffic-bound (640K
// memory-side atomics + random 4B stores = 67 MB fine-grained @1.45 TB/s
// = 46us; MLP batching didn't move it). v11 replaces it with a streaming
// counting sort (P1 here + scatter_edges + build_rows below): global
// atomics -> 0, all traffic streaming or LDS.
// Role 0 (P1): per-block LDS histogram of dst>>8 -> blockhist (coalesced).
// Role 1: x -> fp16. Role 2: weight image (wave-linear). Role 3: query norm.
// Weight image per mat, 32768 halves: [kc4:4][s=ks*4+colgrp:8][lane:64]
// [hi8|lo8]; a wave-iteration reads a dense 2 KB.

__global__ __launch_bounds__(256) void prep_all(
    const int* __restrict__ ei, int E, int* __restrict__ blockhist, int NB,
    const float* __restrict__ x, const float* __restrict__ query,
    const float* __restrict__ Wl, const float* __restrict__ Wr,
    const float* __restrict__ Wlin, _Float16* __restrict__ xh,
    _Float16* __restrict__ wimg, float* __restrict__ qn, int n8, int HB, int SB,
    int WB) {
    int b = blockIdx.x;
    int tid = threadIdx.x;
    if (b < HB) {
        __shared__ int hist[NBUCK_MAX];
        for (int j = tid; j < NB; j += 256) hist[j] = 0;
        __syncthreads();
        int base = b * 2048 + tid;
#pragma unroll
        for (int k = 0; k < 8; ++k) {
            int e = base + k * 256;
            if (e < E) atomicAdd(&hist[ei[E + e] >> 8], 1);
        }
        __syncthreads();
        for (int j = tid; j < NB; j += 256) blockhist[(size_t)b * NB + j] = hist[j];
    } else if (b < HB + SB) {
        int i = (b - HB) * 256 + tid;
        if (i < n8) {
            const float4* x4 = (const float4*)x;
            float4 u = x4[(size_t)i * 2], v = x4[(size_t)i * 2 + 1];
            float f[8] = {u.x, u.y, u.z, u.w, v.x, v.y, v.z, v.w};
            half8 h;
#pragma unroll
            for (int j = 0; j < 8; ++j) h[j] = (_Float16)f[j];
            *(half8*)(xh + (size_t)i * 8) = h;
        }
    } else if (b < HB + SB + WB) {
        int gidx = (b - HB - SB) * 256 + tid;
        if (gidx < 7 * 2048) {
            int mat = gidx / 2048;
            int rem = gidx - mat * 2048;
            int kc4 = rem >> 9;
            int r2 = rem & 511;
            int s = r2 >> 6;
            int lane = r2 & 63;
            int ks = s >> 2;
            int colgrp = s & 3;
            int lhi = lane >> 5, l31 = lane & 31;
            int n = colgrp * 32 + l31;
            int g16 = kc4 * 4 + ks * 2 + lhi;
            const float* src = (mat == 6) ? Wlin
                             : ((mat & 1) ? Wr + (mat >> 1) * H * H
                                          : Wl + (mat >> 1) * H * H);
            const float* p = src + n * H + g16 * 8;
            half8 h, l;
#pragma unroll
            for (int j = 0; j < 8; ++j) {
                float v = p[j];
                _Float16 hh = (_Float16)v;
                h[j] = hh;
                l[j] = (_Float16)(v - (float)hh);
            }
            size_t base = (size_t)mat * 32768 + (size_t)kc4 * 8192 +
                          (size_t)s * 1024 + (size_t)lane * 16;
            *(half8*)(wimg + base) = h;
            *(half8*)(wimg + base + 8) = l;
        }
    } else {
        int g = b - HB - SB - WB;
        __shared__ float part[4];
        float v = (tid < 128) ? query[g * H + tid] : 0.f;
        float ss = v * v;
#pragma unroll
        for (int off = 32; off > 0; off >>= 1) ss += __shfl_xor(ss, off, 64);
        if ((tid & 63) == 0) part[tid >> 6] = ss;
        __syncthreads();
        float tot = part[0] + part[1];
        if (tid < 128) qn[g * H + tid] = v / fmaxf(sqrtf(tot), 1e-12f);
    }
}

// ---------------- P3: scatter edges into bucket regions (no global atomics)
// Each block b derives its exact per-bucket base by scanning blockhist
// columns (L2-cached, redundant across blocks -- no grid sync needed),
// assigns within-(block,bucket) ranks via LDS atomics, and writes (dst,src)
// records to disjoint contiguous regions. Block 0 also publishes
// colstart/coltot for build_rows.

__global__ __launch_bounds__(256) void scatter_edges(
    const int* __restrict__ ei, int E, const int* __restrict__ blockhist,
    int HB, int NB, int2* __restrict__ bucketed, int* __restrict__ colstart,
    int* __restrict__ coltot) {
    __shared__ int sbase[NBUCK_MAX];
    __shared__ int stot[NBUCK_MAX];
    __shared__ int scnt[NBUCK_MAX];
    int b = blockIdx.x;
    int tid = threadIdx.x;

    for (int j = tid; j < NB; j += 256) {
        int off = 0, tot = 0;
        for (int bb = 0; bb < HB; ++bb) {
            int v = blockhist[(size_t)bb * NB + j];
            off += (bb < b) ? v : 0;
            tot += v;
        }
        sbase[j] = off;
        stot[j] = tot;
        scnt[j] = 0;
    }
    __syncthreads();
    if (tid == 0) {  // exclusive scan of stot (NB <= 256, serial is fine)
        int run = 0;
        for (int j = 0; j < NB; ++j) {
            int t = stot[j];
            stot[j] = run;
            run += t;
        }
    }
    __syncthreads();
    for (int j = tid; j < NB; j += 256) {
        sbase[j] += stot[j];
        if (b == 0) {
            colstart[j] = stot[j];
            // recover tot: next prefix - this prefix (or run total for last)
        }
    }
    __syncthreads();
    if (b == 0) {
        for (int j = tid; j < NB; j += 256) {
            int tot = 0;
            for (int bb = 0; bb < HB; ++bb) tot += blockhist[(size_t)bb * NB + j];
            coltot[j] = tot;
        }
    }
    int base = b * 2048 + tid;
#pragma unroll
    for (int k = 0; k < 8; ++k) {
        int e = base + k * 256;
        if (e < E) {
            int s = ei[e];
            int d = ei[E + e];
            int bu = d >> 8;
            int r = atomicAdd(&scnt[bu], 1);
            bucketed[sbase[bu] + r] = make_int2(d, s);
        }
    }
}

// ---------------- P4: build adjacency rows + deg in LDS, dump coalesced ---
// Block k owns nodes [k*256, (k+1)*256): reads its contiguous bucket
// segment, slots via LDS atomics, writes deg + 32-slot rows coalesced.
// Rows zero-initialized (slot-0 read of d==0 nodes stays in-bounds).

__global__ __launch_bounds__(256) void build_rows(
    const int2* __restrict__ bucketed, const int* __restrict__ colstart,
    const int* __restrict__ coltot, int* __restrict__ deg,
    int* __restrict__ adjp32, int* __restrict__ govf, int* __restrict__ ovf,
    int N) {
    __shared__ __align__(16) int rows[256 * 32];  // 32 KB
    __shared__ int cnt[256];
    int k = blockIdx.x;
    int tid = threadIdx.x;
    cnt[tid] = 0;
    for (int j = tid; j < 256 * 32; j += 256) rows[j] = 0;
    __syncthreads();

    int s0 = colstart[k];
    int cn = coltot[k];
    for (int i = tid; i < cn; i += 256) {
        int2 rec = bucketed[s0 + i];
        int dl = rec.x & 255;  // rec.x >> 8 == k by construction
        int sl = atomicAdd(&cnt[dl], 1);
        if (sl < 32) {
            rows[dl * 32 + sl] = rec.y;
        } else {
            int o = atomicAdd(govf, 1);
            ovf[2 * o] = rec.x;
            ovf[2 * o + 1] = rec.y;
        }
    }
    __syncthreads();
    int node0 = k << 8;
    if (node0 + tid < N) deg[node0 + tid] = cnt[tid];
    for (int j = tid; j < 2048; j += 256) {  // int4 quads: 256 rows x 8
        int row = j >> 3, q = j & 7;
        int node = node0 + row;
        if (node < N)
            ((int4*)adjp32)[(size_t)node * 8 + q] = ((const int4*)rows)[row * 8 + q];
    }
}

// ---------------- fused layer v9: 8-wave split, CSR-free gather -----------
// Y = relu(segmax(X) @ Wl^T + bias + X @ Wr^T).
// 512 threads = 8 waves per 32-row tile. Waves 0-3: m@Wl (quarter w&3);
// waves 4-7: x@Wr. Partial f32 accs summed via LDS combine.
// Gather: straight-line 32-slot adjp32 path (slots dense, order-free;
// clamp j<d?j:0; d==0 rows zeroed); d>32 nodes also scan the tiny ovf list
// (wave-uniform branch, ~never taken).

template <bool FINAL_UNUSED>
__global__ __launch_bounds__(512, 8) void layer_fused(
    const half8* __restrict__ Xh, const int* __restrict__ deg,
    const int* __restrict__ adjp32, const int* __restrict__ ovf,
    const int* __restrict__ ovfcnt, const _Float16* __restrict__ Bimg,
    const float* __restrict__ bias, _Float16* __restrict__ Yh, int N) {
    __shared__ __align__(16) unsigned char smem[16384];
    _Float16* sU = (_Float16*)smem;           // m image (32x128, XOR-16), 8 KB
    _Float16* sX = (_Float16*)(smem + 8192);  // x image (32x128, XOR-16), 8 KB
    float* comb = (float*)smem;               // [4][32][32] f32 after GEMM

    int tid = threadIdx.x;
    int w = tid >> 6;   // 0..7
    int wq = w & 3;     // col quarter
    int wh = w >> 2;    // 0: m@Wl, 1: x@Wr
    int lane = tid & 63;
    int l31 = lane & 31;
    int lhi = lane >> 5;
    int n0 = blockIdx.x * 32;

    const half8 hz = {(_Float16)0.f, (_Float16)0.f, (_Float16)0.f, (_Float16)0.f,
                      (_Float16)0.f, (_Float16)0.f, (_Float16)0.f, (_Float16)0.f};

    // ---- stage sX: 512 threads, one half8 each ----
    {
        int row = tid >> 4;
        int g = tid & 15;
        int nn = n0 + row;
        half8 h = hz;
        if (nn < N) h = Xh[(size_t)nn * 16 + g];
        *(half8*)&sX[row * 128 + ((g ^ (row & 15)) << 3)] = h;
    }

    // ---- Phase G: gather segment-max (4 nodes per wave, straight-line) ----
    {
        int sub = lane >> 4;  // neighbor-slot group AND metadata node id
        int lf = lane & 15;
        int nd4 = n0 + w * 4;
        int node = nd4 + sub;
        int nodec = node < N ? node : N - 1;
        int degv = (node < N) ? deg[node] : 0;  // replicated across 16 lanes

        int dmx = degv;
        {
            int t = __shfl_xor(dmx, 16, 64);
            dmx = t > dmx ? t : dmx;
            t = __shfl_xor(dmx, 32, 64);
            dmx = t > dmx ? t : dmx;
        }

        // metadata: lane L holds adjp32[node (L>>4)][slot (L&15)]
        int r0 = adjp32[(size_t)nodec * 32 + lf];
        int r1 = 0;
        if (dmx > 16) r1 = adjp32[(size_t)nodec * 32 + 16 + lf];
#pragma unroll
        for (int i = 0; i < 4; ++i) {
            int d = __shfl(degv, i << 4, 64);
            int base = i << 4;
            int j0 = sub, j1 = 4 + sub, j2 = 8 + sub, j3 = 12 + sub;
            int i0 = __shfl(r0, base | (j0 < d ? j0 : 0), 64);
            int i1 = __shfl(r0, base | (j1 < d ? j1 : 0), 64);
            int i2 = __shfl(r0, base | (j2 < d ? j2 : 0), 64);
            int i3 = __shfl(r0, base | (j3 < d ? j3 : 0), 64);
            half8 v0 = Xh[(size_t)i0 * 16 + lf];
            half8 v1 = Xh[(size_t)i1 * 16 + lf];
            half8 v2 = Xh[(size_t)i2 * 16 + lf];
            half8 v3 = Xh[(size_t)i3 * 16 + lf];
            half8 acc = h8max(h8max(v0, v1), h8max(v2, v3));
            if (d > 16) {  // wave-uniform per node
                int k4 = (16 + sub) < d ? sub : 0;
                int k5 = (20 + sub) < d ? 4 + sub : 0;
                int k6 = (24 + sub) < d ? 8 + sub : 0;
                int k7 = (28 + sub) < d ? 12 + sub : 0;
                int i4 = __shfl(r1, base | k4, 64);
                int i5 = __shfl(r1, base | k5, 64);
                int i6 = __shfl(r1, base | k6, 64);
                int i7 = __shfl(r1, base | k7, 64);
                half8 u0 = Xh[(size_t)i4 * 16 + lf];
                half8 u1 = Xh[(size_t)i5 * 16 + lf];
                half8 u2 = Xh[(size_t)i6 * 16 + lf];
                half8 u3 = Xh[(size_t)i7 * 16 + lf];
                acc = h8max(acc, h8max(h8max(u0, u1), h8max(u2, u3)));
            }
            if (d > 32) {  // wave-uniform; ~never taken (overflow edges)
                int cntv = ovfcnt[0];
                for (int kk = 0; kk < cntv; ++kk) {
                    if (ovf[2 * kk] == nd4 + i) {
                        half8 u = Xh[(size_t)ovf[2 * kk + 1] * 16 + lf];
                        acc = h8max(acc, u);
                    }
                }
            }
            acc = h8max(acc, h8shfl_xor(acc, 16));
            acc = h8max(acc, h8shfl_xor(acc, 32));
            if (d == 0) acc = hz;
            int row = w * 4 + i;
            if (sub == 0) *(half8*)&sU[row * 128 + ((lf ^ (row & 15)) << 3)] = acc;
        }
    }
    __syncthreads();  // B1: sU + sX visible

    f32x16 acc;
    int col = wq * 32 + l31;
    {
        float b0 = (wh == 0) ? bias[col] : 0.f;
#pragma unroll
        for (int r = 0; r < 16; ++r) acc[r] = b0;
    }

    int rl = l31;
    const _Float16* A = wh ? sX : sU;
    const _Float16* B = Bimg + (size_t)wh * 32768;

    // ---- GEMM: each wave 8 iterations (full K, one pass) ----
#pragma unroll
    for (int kc4 = 0; kc4 < 4; ++kc4) {
#pragma unroll
        for (int ks = 0; ks < 2; ++ks) {
            int g16 = kc4 * 4 + ks * 2 + lhi;
            int posA = g16 ^ (rl & 15);
            half8 ah = *(const half8*)&A[rl * 128 + posA * 8];
            size_t boff =
                (size_t)kc4 * 8192 + (size_t)(ks * 4 + wq) * 1024 + (size_t)lane * 16;
            half8 bh = *(const half8*)&B[boff];
            half8 bl2 = *(const half8*)&B[boff + 8];
            acc = __builtin_amdgcn_mfma_f32_32x32x16_f16(ah, bh, acc, 0, 0, 0);
            acc = __builtin_amdgcn_mfma_f32_32x32x16_f16(ah, bl2, acc, 0, 0, 0);
        }
    }

    __syncthreads();  // B2: all sU/sX reads done; smem reusable as comb

    // ---- combine: waves 4-7 write partials, waves 0-3 add ----
    if (wh == 1) {
#pragma unroll
        for (int r = 0; r < 16; ++r) {
            int rloc = (r & 3) + 8 * (r >> 2) + 4 * lhi;
            comb[wq * 1024 + rloc * 32 + l31] = acc[r];
        }
    }
    __syncthreads();  // B3

    if (wh == 0) {
#pragma unroll
        for (int r = 0; r < 16; ++r) {
            int rloc = (r & 3) + 8 * (r >> 2) + 4 * lhi;
            float y = acc[r] + comb[wq * 1024 + rloc * 32 + l31];
            int row = n0 + rloc;
            if (row < N) Yh[(size_t)row * H + col] = (_Float16)fmaxf(y, 0.f);
        }
    }
}

// ---------------- MFMA final linear + cosine ----------------
// Block 256 = 4 waves; 32-row tile; wave-linear Wlin image read dense from
// global (L2-resident).

__global__ __launch_bounds__(256) void final_mfma6(
    const half8* __restrict__ Xh, const _Float16* __restrict__ Bimg,  // Wlin
    const float* __restrict__ blin, const float* __restrict__ qn,
    const int* __restrict__ bv, float* __restrict__ out, int N) {
    __shared__ __align__(16) _Float16 sA[4096];  // 32 rows x 128, XOR-16

    int tid = threadIdx.x;
    int w = tid >> 6;
    int lane = tid & 63;
    int l31 = lane & 31;
    int lhi = lane >> 5;
    int n0 = blockIdx.x * 32;

    {
        const half8 hz = {(_Float16)0.f, (_Float16)0.f, (_Float16)0.f, (_Float16)0.f,
                          (_Float16)0.f, (_Float16)0.f, (_Float16)0.f, (_Float16)0.f};
#pragma unroll
        for (int t = 0; t < 2; ++t) {
            int idx = tid + t * 256;
            int row = idx >> 4;
            int g = idx & 15;
            int nn = n0 + row;
            half8 h = hz;
            if (nn < N) h = Xh[(size_t)nn * 16 + g];
            *(half8*)&sA[row * 128 + ((g ^ (row & 15)) << 3)] = h;
        }
    }

    int arow = n0 + l31;
    arow = arow < N ? arow : N - 1;
    int gl = bv[arow];

    f32x16 acc;
    int col = w * 32 + l31;
    {
        float b = blin[col];
#pragma unroll
        for (int r = 0; r < 16; ++r) acc[r] = b;
    }
    int rl = l31;
    __syncthreads();

#pragma unroll
    for (int kc4 = 0; kc4 < 4; ++kc4) {
#pragma unroll
        for (int ks = 0; ks < 2; ++ks) {
            int g16 = kc4 * 4 + ks * 2 + lhi;
            int posA = g16 ^ (rl & 15);
            half8 ah = *(const half8*)&sA[rl * 128 + posA * 8];
            size_t boff =
                (size_t)kc4 * 8192 + (size_t)(ks * 4 + w) * 1024 + (size_t)lane * 16;
            half8 bh = *(const half8*)&Bimg[boff];
            half8 bl2 = *(const half8*)&Bimg[boff + 8];
            acc = __builtin_amdgcn_mfma_f32_32x32x16_f16(ah, bh, acc, 0, 0, 0);
            acc = __builtin_amdgcn_mfma_f32_32x32x16_f16(ah, bl2, acc, 0, 0, 0);
        }
    }

    // cosine epilogue: per-quarter partials, combine via LDS
    __syncthreads();  // sA reads done; reuse as float scratch
    float* sP = (float*)sA;  // [32 rows][4 quarters][ss,sd] = 1 KB
#pragma unroll
    for (int r = 0; r < 16; ++r) {
        int rloc = (r & 3) + 8 * (r >> 2) + 4 * lhi;
        int g = __shfl(gl, rloc, 32);
        float y = acc[r];
        float q = qn[(size_t)g * H + col];
        float ss = y * y;
        float sd = y * q;
#pragma unroll
        for (int off = 1; off <= 16; off <<= 1) {
            ss += __shfl_xor(ss, off, 64);
            sd += __shfl_xor(sd, off, 64);
        }
        if (l31 == 0) {
            sP[(rloc * 4 + w) * 2] = ss;
            sP[(rloc * 4 + w) * 2 + 1] = sd;
        }
    }
    __syncthreads();
    if (tid < 32) {
        int row = n0 + tid;
        if (row < N) {
            float ss = 0.f, sd = 0.f;
#pragma unroll
            for (int q = 0; q < 4; ++q) {
                ss += sP[(tid * 4 + q) * 2];
                sd += sP[(tid * 4 + q) * 2 + 1];
            }
            out[row] = sd / fmaxf(sqrtf(ss), 1e-12f);
        }
    }
}

// ---------------- launch ----------------

extern "C" void kernel_launch(void* const* d_in, const int* in_sizes, int n_in,
                              void* d_out, int out_size, void* d_ws, size_t ws_size,
                              hipStream_t stream) {
    const float* x = (const float*)d_in[0];
    const float* query = (const float*)d_in[1];
    const float* Wl = (const float*)d_in[2];
    const float* bl = (const float*)d_in[3];
    const float* Wr = (const float*)d_in[4];
    const float* Wlin = (const float*)d_in[5];
    const float* blin = (const float*)d_in[6];
    const int* ei = (const int*)d_in[7];
    const int* bv = (const int*)d_in[8];
    float* out = (float*)d_out;

    const int N = in_sizes[0] / H;
    const int E = in_sizes[7] / 2;
    const int G = in_sizes[1] / H;

    const int HB = (E + 2047) / 2048;  // 8 edges/thread, 256 threads
    const int NB = (N + 255) >> 8;     // coarse buckets (<= NBUCK_MAX)

    char* p = (char*)d_ws;
    auto alloc = [&](size_t bytes) {
        char* r = p;
        p += (bytes + 255) & ~(size_t)255;
        return r;
    };
    int* deg = (int*)alloc((size_t)(N + 1) * sizeof(int));  // deg | govf
    int* govf = deg + N;
    int* adjp32 = (int*)alloc((size_t)N * 32 * sizeof(int));
    int* ovf = (int*)alloc((size_t)E * 2 * sizeof(int));
    int* blockhist = (int*)alloc((size_t)HB * NB * sizeof(int));
    int* colstart = (int*)alloc((size_t)NB * sizeof(int));
    int* coltot = (int*)alloc((size_t)NB * sizeof(int));
    int2* bucketed = (int2*)alloc((size_t)E * sizeof(int2));
    float* qn = (float*)alloc((size_t)G * H * sizeof(float));
    _Float16* wimg = (_Float16*)alloc((size_t)7 * 32768 * sizeof(_Float16));
    size_t actH = (size_t)N * H * sizeof(_Float16);
    _Float16* xah = (_Float16*)alloc(actH);
    _Float16* xbh = (_Float16*)alloc(actH);

    hipMemsetAsync(govf, 0, sizeof(int), stream);

    const int n8 = N * H / 8;
    const int SB = (n8 + 255) / 256;
    const int WB = (7 * 2048 + 255) / 256;
    prep_all<<<HB + SB + WB + G, 256, 0, stream>>>(ei, E, blockhist, NB, x,
                                                   query, Wl, Wr, Wlin, xah,
                                                   wimg, qn, n8, HB, SB, WB);
    scatter_edges<<<HB, 256, 0, stream>>>(ei, E, blockhist, HB, NB, bucketed,
                                          colstart, coltot);
    build_rows<<<NB, 256, 0, stream>>>(bucketed, colstart, coltot, deg, adjp32,
                                       govf, ovf, N);

    const int NGm = (N + 31) / 32;  // 32-row tiles

    layer_fused<false><<<NGm, 512, 0, stream>>>(
        (const half8*)xah, deg, adjp32, ovf, govf, wimg + (size_t)0 * 65536,
        bl + 0 * H, xbh, N);
    layer_fused<false><<<NGm, 512, 0, stream>>>(
        (const half8*)xbh, deg, adjp32, ovf, govf, wimg + (size_t)1 * 65536,
        bl + 1 * H, xah, N);
    layer_fused<false><<<NGm, 512, 0, stream>>>(
        (const half8*)xah, deg, adjp32, ovf, govf, wimg + (size_t)2 * 65536,
        bl + 2 * H, xbh, N);
    final_mfma6<<<NGm, 256, 0, stream>>>(
        (const half8*)xbh, wimg + (size_t)6 * 32768, blin, qn, bv, out, N);
}

// Round 11
// 231.179 us; speedup vs baseline: 1.4330x; 1.4330x over previous
//
#include <hip/hip_runtime.h>
#include <math.h>

#define H 128
#define NBUCK_MAX 256  // coarse buckets = (N+255)>>8; requires N <= 65536

typedef _Float16 half8 __attribute__((ext_vector_type(8)));
typedef float f32x16 __attribute__((ext_vector_type(16)));
typedef int int4v __attribute__((ext_vector_type(4)));

__device__ __forceinline__ half8 h8max(half8 a, half8 b) {
#if defined(__has_builtin) && __has_builtin(__builtin_elementwise_max)
    return __builtin_elementwise_max(a, b);
#else
    half8 r;
#pragma unroll
    for (int j = 0; j < 8; ++j) r[j] = a[j] > b[j] ? a[j] : b[j];
    return r;
#endif
}

__device__ __forceinline__ half8 h8shfl_xor(half8 v, int mask) {
    int4v iv;
    __builtin_memcpy(&iv, &v, 16);
#pragma unroll
    for (int j = 0; j < 4; ++j) iv[j] = __shfl_xor(iv[j], mask, 64);
    half8 r;
    __builtin_memcpy(&r, &iv, 16);
    return r;
}

// ---------------- merged prep ----------------
// Counting-sort CSR-free build (v12): P1 block-histogram here; then
// scan_hist (parallel column scans -- round-10's scatter_edges spent 115us
// on redundant SERIAL per-block column scans, now done once in parallel),
// scan_buckets, scatter_edges (LDS-ranked, no global atomics), build_rows.
// Role 1: x -> fp16. Role 2: weight image (wave-linear). Role 3: query norm.

__global__ __launch_bounds__(256) void prep_all(
    const int* __restrict__ ei, int E, int* __restrict__ blockhist, int NB,
    const float* __restrict__ x, const float* __restrict__ query,
    const float* __restrict__ Wl, const float* __restrict__ Wr,
    const float* __restrict__ Wlin, _Float16* __restrict__ xh,
    _Float16* __restrict__ wimg, float* __restrict__ qn, int n8, int HB, int SB,
    int WB) {
    int b = blockIdx.x;
    int tid = threadIdx.x;
    if (b < HB) {
        __shared__ int hist[NBUCK_MAX];
        for (int j = tid; j < NB; j += 256) hist[j] = 0;
        __syncthreads();
        int base = b * 2048 + tid;
#pragma unroll
        for (int k = 0; k < 8; ++k) {
            int e = base + k * 256;
            if (e < E) atomicAdd(&hist[ei[E + e] >> 8], 1);
        }
        __syncthreads();
        for (int j = tid; j < NB; j += 256) blockhist[(size_t)b * NB + j] = hist[j];
    } else if (b < HB + SB) {
        int i = (b - HB) * 256 + tid;
        if (i < n8) {
            const float4* x4 = (const float4*)x;
            float4 u = x4[(size_t)i * 2], v = x4[(size_t)i * 2 + 1];
            float f[8] = {u.x, u.y, u.z, u.w, v.x, v.y, v.z, v.w};
            half8 h;
#pragma unroll
            for (int j = 0; j < 8; ++j) h[j] = (_Float16)f[j];
            *(half8*)(xh + (size_t)i * 8) = h;
        }
    } else if (b < HB + SB + WB) {
        int gidx = (b - HB - SB) * 256 + tid;
        if (gidx < 7 * 2048) {
            int mat = gidx / 2048;
            int rem = gidx - mat * 2048;
            int kc4 = rem >> 9;
            int r2 = rem & 511;
            int s = r2 >> 6;
            int lane = r2 & 63;
            int ks = s >> 2;
            int colgrp = s & 3;
            int lhi = lane >> 5, l31 = lane & 31;
            int n = colgrp * 32 + l31;
            int g16 = kc4 * 4 + ks * 2 + lhi;
            const float* src = (mat == 6) ? Wlin
                             : ((mat & 1) ? Wr + (mat >> 1) * H * H
                                          : Wl + (mat >> 1) * H * H);
            const float* p = src + n * H + g16 * 8;
            half8 h, l;
#pragma unroll
            for (int j = 0; j < 8; ++j) {
                float v = p[j];
                _Float16 hh = (_Float16)v;
                h[j] = hh;
                l[j] = (_Float16)(v - (float)hh);
            }
            size_t base = (size_t)mat * 32768 + (size_t)kc4 * 8192 +
                          (size_t)s * 1024 + (size_t)lane * 16;
            *(half8*)(wimg + base) = h;
            *(half8*)(wimg + base + 8) = l;
        }
    } else {
        int g = b - HB - SB - WB;
        __shared__ float part[4];
        float v = (tid < 128) ? query[g * H + tid] : 0.f;
        float ss = v * v;
#pragma unroll
        for (int off = 32; off > 0; off >>= 1) ss += __shfl_xor(ss, off, 64);
        if ((tid & 63) == 0) part[tid >> 6] = ss;
        __syncthreads();
        float tot = part[0] + part[1];
        if (tid < 128) qn[g * H + tid] = v / fmaxf(sqrtf(tot), 1e-12f);
    }
}

// ---------------- P2a: per-bucket column scan (parallel, once) ------------
// Block j: exclusive scan of blockhist[:,j] over HB entries (512-wide
// Hillis-Steele chunks with carry), written back IN PLACE; coltot[j]=total.

__global__ __launch_bounds__(512) void scan_hist(int* __restrict__ blockhist,
                                                 int HB, int NB,
                                                 int* __restrict__ coltot) {
    __shared__ int buf[512];
    int j = blockIdx.x;
    int tid = threadIdx.x;
    int carry = 0;
    for (int base = 0; base < HB; base += 512) {
        int t = base + tid;
        int v = (t < HB) ? blockhist[(size_t)t * NB + j] : 0;
        buf[tid] = v;
        __syncthreads();
        int incl = v;
#pragma unroll
        for (int off = 1; off < 512; off <<= 1) {
            int u = (tid >= off) ? buf[tid - off] : 0;
            __syncthreads();
            incl += u;
            buf[tid] = incl;
            __syncthreads();
        }
        if (t < HB) blockhist[(size_t)t * NB + j] = carry + incl - v;
        carry += buf[511];
        __syncthreads();
    }
    if (tid == 0) coltot[j] = carry;
}

// ---------------- P2b: bucket-level exclusive scan (1 block) --------------

__global__ __launch_bounds__(256) void scan_buckets(const int* __restrict__ coltot,
                                                    int NB,
                                                    int* __restrict__ colstart) {
    __shared__ int buf[256];
    int tid = threadIdx.x;
    int v = (tid < NB) ? coltot[tid] : 0;
    buf[tid] = v;
    __syncthreads();
    int incl = v;
#pragma unroll
    for (int off = 1; off < 256; off <<= 1) {
        int u = (tid >= off) ? buf[tid - off] : 0;
        __syncthreads();
        incl += u;
        buf[tid] = incl;
        __syncthreads();
    }
    if (tid < NB) colstart[tid] = incl - v;
}

// ---------------- P3: scatter edges into bucket regions -------------------
// Base per (block,bucket) = colstart[j] + scanned blockhist[b][j] (one
// coalesced load each); ranks via LDS atomics; records land in ~10-entry
// contiguous runs per bucket. Zero global atomics.

__global__ __launch_bounds__(256) void scatter_edges(
    const int* __restrict__ ei, int E, const int* __restrict__ blockhist,
    const int* __restrict__ colstart, int NB, int2* __restrict__ bucketed) {
    __shared__ int sbase[NBUCK_MAX];
    __shared__ int scnt[NBUCK_MAX];
    int b = blockIdx.x;
    int tid = threadIdx.x;
    for (int j = tid; j < NB; j += 256) {
        sbase[j] = colstart[j] + blockhist[(size_t)b * NB + j];
        scnt[j] = 0;
    }
    __syncthreads();
    int base = b * 2048 + tid;
#pragma unroll
    for (int k = 0; k < 8; ++k) {
        int e = base + k * 256;
        if (e < E) {
            int s = ei[e];
            int d = ei[E + e];
            int bu = d >> 8;
            int r = atomicAdd(&scnt[bu], 1);
            bucketed[sbase[bu] + r] = make_int2(d, s);
        }
    }
}

// ---------------- P4: build adjacency rows + deg in LDS, dump coalesced ---
// Block k owns nodes [k*256, (k+1)*256): reads its contiguous bucket
// segment, slots via LDS atomics, writes deg + 32-slot rows coalesced.

__global__ __launch_bounds__(256) void build_rows(
    const int2* __restrict__ bucketed, const int* __restrict__ colstart,
    const int* __restrict__ coltot, int* __restrict__ deg,
    int* __restrict__ adjp32, int* __restrict__ govf, int* __restrict__ ovf,
    int N) {
    __shared__ __align__(16) int rows[256 * 32];  // 32 KB
    __shared__ int cnt[256];
    int k = blockIdx.x;
    int tid = threadIdx.x;
    cnt[tid] = 0;
    for (int j = tid; j < 256 * 32; j += 256) rows[j] = 0;
    __syncthreads();

    int s0 = colstart[k];
    int cn = coltot[k];
    for (int i = tid; i < cn; i += 256) {
        int2 rec = bucketed[s0 + i];
        int dl = rec.x & 255;  // rec.x >> 8 == k by construction
        int sl = atomicAdd(&cnt[dl], 1);
        if (sl < 32) {
            rows[dl * 32 + sl] = rec.y;
        } else {
            int o = atomicAdd(govf, 1);
            ovf[2 * o] = rec.x;
            ovf[2 * o + 1] = rec.y;
        }
    }
    __syncthreads();
    int node0 = k << 8;
    if (node0 + tid < N) deg[node0 + tid] = cnt[tid];
    for (int j = tid; j < 2048; j += 256) {  // int4 quads: 256 rows x 8
        int row = j >> 3, q = j & 7;
        int node = node0 + row;
        if (node < N)
            ((int4*)adjp32)[(size_t)node * 8 + q] = ((const int4*)rows)[row * 8 + q];
    }
}

// ---------------- fused layer v9: 8-wave split, CSR-free gather -----------
// Y = relu(segmax(X) @ Wl^T + bias + X @ Wr^T).
// 512 threads = 8 waves per 32-row tile. Waves 0-3: m@Wl (quarter w&3);
// waves 4-7: x@Wr. Partial f32 accs summed via LDS combine.
// Gather: straight-line 32-slot adjp32 path (slots dense, order-free;
// clamp j<d?j:0; d==0 rows zeroed); d>32 nodes also scan the tiny ovf list
// (wave-uniform branch, ~never taken).

template <bool FINAL_UNUSED>
__global__ __launch_bounds__(512, 8) void layer_fused(
    const half8* __restrict__ Xh, const int* __restrict__ deg,
    const int* __restrict__ adjp32, const int* __restrict__ ovf,
    const int* __restrict__ ovfcnt, const _Float16* __restrict__ Bimg,
    const float* __restrict__ bias, _Float16* __restrict__ Yh, int N) {
    __shared__ __align__(16) unsigned char smem[16384];
    _Float16* sU = (_Float16*)smem;           // m image (32x128, XOR-16), 8 KB
    _Float16* sX = (_Float16*)(smem + 8192);  // x image (32x128, XOR-16), 8 KB
    float* comb = (float*)smem;               // [4][32][32] f32 after GEMM

    int tid = threadIdx.x;
    int w = tid >> 6;   // 0..7
    int wq = w & 3;     // col quarter
    int wh = w >> 2;    // 0: m@Wl, 1: x@Wr
    int lane = tid & 63;
    int l31 = lane & 31;
    int lhi = lane >> 5;
    int n0 = blockIdx.x * 32;

    const half8 hz = {(_Float16)0.f, (_Float16)0.f, (_Float16)0.f, (_Float16)0.f,
                      (_Float16)0.f, (_Float16)0.f, (_Float16)0.f, (_Float16)0.f};

    // ---- stage sX: 512 threads, one half8 each ----
    {
        int row = tid >> 4;
        int g = tid & 15;
        int nn = n0 + row;
        half8 h = hz;
        if (nn < N) h = Xh[(size_t)nn * 16 + g];
        *(half8*)&sX[row * 128 + ((g ^ (row & 15)) << 3)] = h;
    }

    // ---- Phase G: gather segment-max (4 nodes per wave, straight-line) ----
    {
        int sub = lane >> 4;  // neighbor-slot group AND metadata node id
        int lf = lane & 15;
        int nd4 = n0 + w * 4;
        int node = nd4 + sub;
        int nodec = node < N ? node : N - 1;
        int degv = (node < N) ? deg[node] : 0;  // replicated across 16 lanes

        int dmx = degv;
        {
            int t = __shfl_xor(dmx, 16, 64);
            dmx = t > dmx ? t : dmx;
            t = __shfl_xor(dmx, 32, 64);
            dmx = t > dmx ? t : dmx;
        }

        // metadata: lane L holds adjp32[node (L>>4)][slot (L&15)]
        int r0 = adjp32[(size_t)nodec * 32 + lf];
        int r1 = 0;
        if (dmx > 16) r1 = adjp32[(size_t)nodec * 32 + 16 + lf];
#pragma unroll
        for (int i = 0; i < 4; ++i) {
            int d = __shfl(degv, i << 4, 64);
            int base = i << 4;
            int j0 = sub, j1 = 4 + sub, j2 = 8 + sub, j3 = 12 + sub;
            int i0 = __shfl(r0, base | (j0 < d ? j0 : 0), 64);
            int i1 = __shfl(r0, base | (j1 < d ? j1 : 0), 64);
            int i2 = __shfl(r0, base | (j2 < d ? j2 : 0), 64);
            int i3 = __shfl(r0, base | (j3 < d ? j3 : 0), 64);
            half8 v0 = Xh[(size_t)i0 * 16 + lf];
            half8 v1 = Xh[(size_t)i1 * 16 + lf];
            half8 v2 = Xh[(size_t)i2 * 16 + lf];
            half8 v3 = Xh[(size_t)i3 * 16 + lf];
            half8 acc = h8max(h8max(v0, v1), h8max(v2, v3));
            if (d > 16) {  // wave-uniform per node
                int k4 = (16 + sub) < d ? sub : 0;
                int k5 = (20 + sub) < d ? 4 + sub : 0;
                int k6 = (24 + sub) < d ? 8 + sub : 0;
                int k7 = (28 + sub) < d ? 12 + sub : 0;
                int i4 = __shfl(r1, base | k4, 64);
                int i5 = __shfl(r1, base | k5, 64);
                int i6 = __shfl(r1, base | k6, 64);
                int i7 = __shfl(r1, base | k7, 64);
                half8 u0 = Xh[(size_t)i4 * 16 + lf];
                half8 u1 = Xh[(size_t)i5 * 16 + lf];
                half8 u2 = Xh[(size_t)i6 * 16 + lf];
                half8 u3 = Xh[(size_t)i7 * 16 + lf];
                acc = h8max(acc, h8max(h8max(u0, u1), h8max(u2, u3)));
            }
            if (d > 32) {  // wave-uniform; ~never taken (overflow edges)
                int cntv = ovfcnt[0];
                for (int kk = 0; kk < cntv; ++kk) {
                    if (ovf[2 * kk] == nd4 + i) {
                        half8 u = Xh[(size_t)ovf[2 * kk + 1] * 16 + lf];
                        acc = h8max(acc, u);
                    }
                }
            }
            acc = h8max(acc, h8shfl_xor(acc, 16));
            acc = h8max(acc, h8shfl_xor(acc, 32));
            if (d == 0) acc = hz;
            int row = w * 4 + i;
            if (sub == 0) *(half8*)&sU[row * 128 + ((lf ^ (row & 15)) << 3)] = acc;
        }
    }
    __syncthreads();  // B1: sU + sX visible

    f32x16 acc;
    int col = wq * 32 + l31;
    {
        float b0 = (wh == 0) ? bias[col] : 0.f;
#pragma unroll
        for (int r = 0; r < 16; ++r) acc[r] = b0;
    }

    int rl = l31;
    const _Float16* A = wh ? sX : sU;
    const _Float16* B = Bimg + (size_t)wh * 32768;

    // ---- GEMM: each wave 8 iterations (full K, one pass) ----
#pragma unroll
    for (int kc4 = 0; kc4 < 4; ++kc4) {
#pragma unroll
        for (int ks = 0; ks < 2; ++ks) {
            int g16 = kc4 * 4 + ks * 2 + lhi;
            int posA = g16 ^ (rl & 15);
            half8 ah = *(const half8*)&A[rl * 128 + posA * 8];
            size_t boff =
                (size_t)kc4 * 8192 + (size_t)(ks * 4 + wq) * 1024 + (size_t)lane * 16;
            half8 bh = *(const half8*)&B[boff];
            half8 bl2 = *(const half8*)&B[boff + 8];
            acc = __builtin_amdgcn_mfma_f32_32x32x16_f16(ah, bh, acc, 0, 0, 0);
            acc = __builtin_amdgcn_mfma_f32_32x32x16_f16(ah, bl2, acc, 0, 0, 0);
        }
    }

    __syncthreads();  // B2: all sU/sX reads done; smem reusable as comb

    // ---- combine: waves 4-7 write partials, waves 0-3 add ----
    if (wh == 1) {
#pragma unroll
        for (int r = 0; r < 16; ++r) {
            int rloc = (r & 3) + 8 * (r >> 2) + 4 * lhi;
            comb[wq * 1024 + rloc * 32 + l31] = acc[r];
        }
    }
    __syncthreads();  // B3

    if (wh == 0) {
#pragma unroll
        for (int r = 0; r < 16; ++r) {
            int rloc = (r & 3) + 8 * (r >> 2) + 4 * lhi;
            float y = acc[r] + comb[wq * 1024 + rloc * 32 + l31];
            int row = n0 + rloc;
            if (row < N) Yh[(size_t)row * H + col] = (_Float16)fmaxf(y, 0.f);
        }
    }
}

// ---------------- MFMA final linear + cosine ----------------
// Block 256 = 4 waves; 32-row tile; wave-linear Wlin image read dense from
// global (L2-resident).

__global__ __launch_bounds__(256) void final_mfma6(
    const half8* __restrict__ Xh, const _Float16* __restrict__ Bimg,  // Wlin
    const float* __restrict__ blin, const float* __restrict__ qn,
    const int* __restrict__ bv, float* __restrict__ out, int N) {
    __shared__ __align__(16) _Float16 sA[4096];  // 32 rows x 128, XOR-16

    int tid = threadIdx.x;
    int w = tid >> 6;
    int lane = tid & 63;
    int l31 = lane & 31;
    int lhi = lane >> 5;
    int n0 = blockIdx.x * 32;

    {
        const half8 hz = {(_Float16)0.f, (_Float16)0.f, (_Float16)0.f, (_Float16)0.f,
                          (_Float16)0.f, (_Float16)0.f, (_Float16)0.f, (_Float16)0.f};
#pragma unroll
        for (int t = 0; t < 2; ++t) {
            int idx = tid + t * 256;
            int row = idx >> 4;
            int g = idx & 15;
            int nn = n0 + row;
            half8 h = hz;
            if (nn < N) h = Xh[(size_t)nn * 16 + g];
            *(half8*)&sA[row * 128 + ((g ^ (row & 15)) << 3)] = h;
        }
    }

    int arow = n0 + l31;
    arow = arow < N ? arow : N - 1;
    int gl = bv[arow];

    f32x16 acc;
    int col = w * 32 + l31;
    {
        float b = blin[col];
#pragma unroll
        for (int r = 0; r < 16; ++r) acc[r] = b;
    }
    int rl = l31;
    __syncthreads();

#pragma unroll
    for (int kc4 = 0; kc4 < 4; ++kc4) {
#pragma unroll
        for (int ks = 0; ks < 2; ++ks) {
            int g16 = kc4 * 4 + ks * 2 + lhi;
            int posA = g16 ^ (rl & 15);
            half8 ah = *(const half8*)&sA[rl * 128 + posA * 8];
            size_t boff =
                (size_t)kc4 * 8192 + (size_t)(ks * 4 + w) * 1024 + (size_t)lane * 16;
            half8 bh = *(const half8*)&Bimg[boff];
            half8 bl2 = *(const half8*)&Bimg[boff + 8];
            acc = __builtin_amdgcn_mfma_f32_32x32x16_f16(ah, bh, acc, 0, 0, 0);
            acc = __builtin_amdgcn_mfma_f32_32x32x16_f16(ah, bl2, acc, 0, 0, 0);
        }
    }

    // cosine epilogue: per-quarter partials, combine via LDS
    __syncthreads();  // sA reads done; reuse as float scratch
    float* sP = (float*)sA;  // [32 rows][4 quarters][ss,sd] = 1 KB
#pragma unroll
    for (int r = 0; r < 16; ++r) {
        int rloc = (r & 3) + 8 * (r >> 2) + 4 * lhi;
        int g = __shfl(gl, rloc, 32);
        float y = acc[r];
        float q = qn[(size_t)g * H + col];
        float ss = y * y;
        float sd = y * q;
#pragma unroll
        for (int off = 1; off <= 16; off <<= 1) {
            ss += __shfl_xor(ss, off, 64);
            sd += __shfl_xor(sd, off, 64);
        }
        if (l31 == 0) {
            sP[(rloc * 4 + w) * 2] = ss;
            sP[(rloc * 4 + w) * 2 + 1] = sd;
        }
    }
    __syncthreads();
    if (tid < 32) {
        int row = n0 + tid;
        if (row < N) {
            float ss = 0.f, sd = 0.f;
#pragma unroll
            for (int q = 0; q < 4; ++q) {
                ss += sP[(tid * 4 + q) * 2];
                sd += sP[(tid * 4 + q) * 2 + 1];
            }
            out[row] = sd / fmaxf(sqrtf(ss), 1e-12f);
        }
    }
}

// ---------------- launch ----------------

extern "C" void kernel_launch(void* const* d_in, const int* in_sizes, int n_in,
                              void* d_out, int out_size, void* d_ws, size_t ws_size,
                              hipStream_t stream) {
    const float* x = (const float*)d_in[0];
    const float* query = (const float*)d_in[1];
    const float* Wl = (const float*)d_in[2];
    const float* bl = (const float*)d_in[3];
    const float* Wr = (const float*)d_in[4];
    const float* Wlin = (const float*)d_in[5];
    const float* blin = (const float*)d_in[6];
    const int* ei = (const int*)d_in[7];
    const int* bv = (const int*)d_in[8];
    float* out = (float*)d_out;

    const int N = in_sizes[0] / H;
    const int E = in_sizes[7] / 2;
    const int G = in_sizes[1] / H;

    const int HB = (E + 2047) / 2048;  // 8 edges/thread, 256 threads
    const int NB = (N + 255) >> 8;     // coarse buckets (<= NBUCK_MAX)

    char* p = (char*)d_ws;
    auto alloc = [&](size_t bytes) {
        char* r = p;
        p += (bytes + 255) & ~(size_t)255;
        return r;
    };
    int* deg = (int*)alloc((size_t)(N + 1) * sizeof(int));  // deg | govf
    int* govf = deg + N;
    int* adjp32 = (int*)alloc((size_t)N * 32 * sizeof(int));
    int* ovf = (int*)alloc((size_t)E * 2 * sizeof(int));
    int* blockhist = (int*)alloc((size_t)HB * NB * sizeof(int));
    int* colstart = (int*)alloc((size_t)NB * sizeof(int));
    int* coltot = (int*)alloc((size_t)NB * sizeof(int));
    int2* bucketed = (int2*)alloc((size_t)E * sizeof(int2));
    float* qn = (float*)alloc((size_t)G * H * sizeof(float));
    _Float16* wimg = (_Float16*)alloc((size_t)7 * 32768 * sizeof(_Float16));
    size_t actH = (size_t)N * H * sizeof(_Float16);
    _Float16* xah = (_Float16*)alloc(actH);
    _Float16* xbh = (_Float16*)alloc(actH);

    hipMemsetAsync(govf, 0, sizeof(int), stream);

    const int n8 = N * H / 8;
    const int SB = (n8 + 255) / 256;
    const int WB = (7 * 2048 + 255) / 256;
    prep_all<<<HB + SB + WB + G, 256, 0, stream>>>(ei, E, blockhist, NB, x,
                                                   query, Wl, Wr, Wlin, xah,
                                                   wimg, qn, n8, HB, SB, WB);
    scan_hist<<<NB, 512, 0, stream>>>(blockhist, HB, NB, coltot);
    scan_buckets<<<1, 256, 0, stream>>>(coltot, NB, colstart);
    scatter_edges<<<HB, 256, 0, stream>>>(ei, E, blockhist, colstart, NB,
                                          bucketed);
    build_rows<<<NB, 256, 0, stream>>>(bucketed, colstart, coltot, deg, adjp32,
                                       govf, ovf, N);

    const int NGm = (N + 31) / 32;  // 32-row tiles

    layer_fused<false><<<NGm, 512, 0, stream>>>(
        (const half8*)xah, deg, adjp32, ovf, govf, wimg + (size_t)0 * 65536,
        bl + 0 * H, xbh, N);
    layer_fused<false><<<NGm, 512, 0, stream>>>(
        (const half8*)xbh, deg, adjp32, ovf, govf, wimg + (size_t)1 * 65536,
        bl + 1 * H, xah, N);
    layer_fused<false><<<NGm, 512, 0, stream>>>(
        (const half8*)xah, deg, adjp32, ovf, govf, wimg + (size_t)2 * 65536,
        bl + 2 * H, xbh, N);
    final_mfma6<<<NGm, 256, 0, stream>>>(
        (const half8*)xbh, wimg + (size_t)6 * 32768, blin, qn, bv, out, N);
}